// Round 1
// baseline (26085.330 us; speedup 1.0000x reference)
//
#include <hip/hip_runtime.h>

// LSTM decoder w/ Bahdanau attention, MI355X.
// Design: persistent grid-synchronized kernel, 256 blocks x 512 threads (1 block/CU).
//   keys = enc @ Wk^T precomputed by a separate tiled GEMM kernel.
//   Per step t (3 hand-rolled grid barriers):
//     P0: q(t) = h_{t-1} @ Wq^T  (+ out(t-1) = h_{t-1} @ Wfc^T + b_fc)
//     P1: attention: e = tanh(q+keys)?v, unnormalized softmax (exp w/o max-sub; |e|<=13),
//         atomicAdd context partials + denominator (4 sub-blocks per batch elem)
//     P2: gates = [x_t, ctx, h] @ [Wih|Whh]^T + bias; LSTM pointwise; h/c update.
//         Gate weights persistent in REGISTERS (68 fp32/thread), inputs broadcast from LDS.
// Barrier: monotonic per-block flag + signed >= compare (0xAA poison is negative -> safe).

#define B 64
#define T 128
#define IN_DIM 64
#define TE 256
#define HID 512
#define ATTN 256
#define OUTD 64
#define KIN 1088   // 576 (x,ctx) + 512 (h)
#define G 256      // main grid blocks
#define BS 512     // main block threads

__device__ __forceinline__ float fast_exp(float x) {
  return __builtin_amdgcn_exp2f(x * 1.44269504f);
}
__device__ __forceinline__ float fast_tanh(float x) {
  float ax = fabsf(x);
  float z = __builtin_amdgcn_exp2f(ax * -2.885390082f);  // e^{-2|x|}
  float r = (1.f - z) * __builtin_amdgcn_rcpf(1.f + z);
  return copysignf(r, x);
}
__device__ __forceinline__ float fast_sig(float x) {
  float z = __builtin_amdgcn_exp2f(x * -1.44269504f);    // e^{-x}
  return __builtin_amdgcn_rcpf(1.f + z);
}

__device__ __forceinline__ void gridbar(int* flags, int seq, int bid, int tid) {
  __syncthreads();
  __threadfence();
  if (tid == 0)
    __hip_atomic_store(&flags[bid], seq, __ATOMIC_RELEASE, __HIP_MEMORY_SCOPE_AGENT);
  if (tid < G) {
    while (__hip_atomic_load(&flags[tid], __ATOMIC_ACQUIRE, __HIP_MEMORY_SCOPE_AGENT) < seq) {
      __builtin_amdgcn_s_sleep(2);
    }
  }
  __syncthreads();
}

// ---- keys[b][e][a] = sum_k enc[b][e][k] * Wk[a][k] ----
// grid: 64 b * 16 e-tiles = 1024 blocks, 256 threads.
__global__ __launch_bounds__(256, 2) void keys_kernel(
    const float* __restrict__ enc, const float* __restrict__ Wk,
    float* __restrict__ keys) {
  __shared__ float et[16][512];   // enc tile, full K
  __shared__ float wk[32][256];   // k-major Wk chunk (reads conflict-free: stride-256 rows)
  const int tid = threadIdx.x;
  const int b = blockIdx.x >> 4;
  const int e0 = (blockIdx.x & 15) * 16;

  // stage enc tile
  for (int p = 0; p < 8; ++p) {
    int i = p * 256 + tid;
    int e = i >> 7, kq = i & 127;
    float4 vv = *(const float4*)&enc[((size_t)(b * TE + e0 + e)) * HID + kq * 4];
    *(float4*)&et[e][kq * 4] = vv;
  }

  float acc[8][2];
  #pragma unroll
  for (int i = 0; i < 8; ++i) { acc[i][0] = 0.f; acc[i][1] = 0.f; }
  const int a0 = tid & 127;
  const int eh = (tid >> 7) * 8;

  for (int kc = 0; kc < 512; kc += 32) {
    __syncthreads();
    for (int p = 0; p < 8; ++p) {
      int i = p * 256 + tid;
      int a = i >> 3, j4 = (i & 7) * 4;
      float4 w4 = *(const float4*)&Wk[(size_t)a * HID + kc + j4];
      wk[j4 + 0][a] = w4.x; wk[j4 + 1][a] = w4.y;
      wk[j4 + 2][a] = w4.z; wk[j4 + 3][a] = w4.w;
    }
    __syncthreads();
    for (int k = 0; k < 32; ++k) {
      float w0 = wk[k][a0], w1 = wk[k][a0 + 128];
      #pragma unroll
      for (int i = 0; i < 8; ++i) {
        float ev = et[eh + i][kc + k];
        acc[i][0] = fmaf(ev, w0, acc[i][0]);
        acc[i][1] = fmaf(ev, w1, acc[i][1]);
      }
    }
  }
  #pragma unroll
  for (int i = 0; i < 8; ++i) {
    keys[((size_t)(b * TE + e0 + eh + i)) * ATTN + a0] = acc[i][0];
    keys[((size_t)(b * TE + e0 + eh + i)) * ATTN + a0 + 128] = acc[i][1];
  }
}

__global__ __launch_bounds__(BS, 2) void main_kernel(
    const float* __restrict__ x, const float* __restrict__ enc,
    const float* __restrict__ Wq, const float* __restrict__ v,
    const float* __restrict__ Wih, const float* __restrict__ Whh,
    const float* __restrict__ bih, const float* __restrict__ bhh,
    const float* __restrict__ Wfc, const float* __restrict__ bfc,
    const float* __restrict__ keys,
    float* hbuf, float* cbuf, float* qbuf, float* ctxb, float* denb,
    int* flags, float* out) {
  const int bid = blockIdx.x, tid = threadIdx.x;

  // P2 role: rg = hidden-slice [rg*8,+8), bg = batch group [bg*16,+16)
  const int rg = bid >> 2;
  const int bg = bid & 3;
  const int r_loc = tid & 31;               // row-local: gate = r>>3, hu = r&7
  const int ks = tid >> 5;                  // k-slice [ks*68, +68)
  const int grow = (r_loc >> 3) * 512 + rg * 8 + (r_loc & 7);  // global gate row

  __shared__ float ilds[8][KIN];            // 34.8 KB staged inputs (8 batch)
  __shared__ float parts[8][16][33];        // 16.9 KB dot partials [bb][ks][r]
  __shared__ float glds[16][32];            // gate values [bb16][r]
  __shared__ float lw[64];                  // P1 exp weights
  __shared__ float p0red[64][9];            // P0 reduce scratch
  __shared__ float blds[32];                // biases for this block's rows
  __shared__ float linv[16];                // 1/den per batch in group

  // ---- prologue: persistent weight registers, biases, v, zero state ----
  float wreg[68];
  #pragma unroll
  for (int i = 0; i < 68; ++i) {
    const int k = ks * 68 + i;
    wreg[i] = (k < 576) ? Wih[(size_t)grow * 576 + k]
                        : Whh[(size_t)grow * 512 + (k - 576)];
  }
  if (tid < 32) {
    const int gr2 = (tid >> 3) * 512 + rg * 8 + (tid & 7);
    blds[tid] = bih[gr2] + bhh[gr2];
  }
  float vv4[4];
  {
    const int lane = tid & 63;
    #pragma unroll
    for (int j = 0; j < 4; ++j) vv4[j] = v[lane + 64 * j];
  }
  // zero [hbuf(2) | cbuf | qbuf | ctxb(2) | den(2)] = 180352 floats
  for (int i = bid * BS + tid; i < 180352; i += G * BS) hbuf[i] = 0.f;

  int seq = 1;
  gridbar(flags, seq, bid, tid);

  for (int t = 0; t < T; ++t) {
    // ---------------- P0: q(t) and out(t-1) ----------------
    {
      const float* hprev = hbuf + (size_t)(t & 1) * B * HID;
      const int b4 = bid >> 4, a16 = bid & 15;
      {
        const int d = tid >> 3, kp = tid & 7;
        const int qb = b4 * 4 + (d >> 4), qa = a16 * 16 + (d & 15);
        const float* hr = hprev + qb * HID + kp * 64;
        const float* wr = Wq + (size_t)qa * HID + kp * 64;
        float acc = 0.f;
        #pragma unroll
        for (int i = 0; i < 16; ++i) {
          float4 h4 = ((const float4*)hr)[i];
          float4 w4 = ((const float4*)wr)[i];
          acc = fmaf(h4.x, w4.x, acc); acc = fmaf(h4.y, w4.y, acc);
          acc = fmaf(h4.z, w4.z, acc); acc = fmaf(h4.w, w4.w, acc);
        }
        p0red[d][kp] = acc;
      }
      __syncthreads();
      if (tid < 64) {
        float s = 0.f;
        #pragma unroll
        for (int j = 0; j < 8; ++j) s += p0red[tid][j];
        qbuf[(b4 * 4 + (tid >> 4)) * ATTN + a16 * 16 + (tid & 15)] = s;
      }
      if (t >= 1) {
        __syncthreads();
        if (tid < 128) {
          const int d2 = tid >> 3, kp = tid & 7;
          const int ob = b4 * 4 + (d2 >> 2), oo = a16 * 4 + (d2 & 3);
          const float* hr = hprev + ob * HID + kp * 64;
          const float* wr = Wfc + (size_t)oo * HID + kp * 64;
          float acc = 0.f;
          #pragma unroll
          for (int i = 0; i < 16; ++i) {
            float4 h4 = ((const float4*)hr)[i];
            float4 w4 = ((const float4*)wr)[i];
            acc = fmaf(h4.x, w4.x, acc); acc = fmaf(h4.y, w4.y, acc);
            acc = fmaf(h4.z, w4.z, acc); acc = fmaf(h4.w, w4.w, acc);
          }
          p0red[d2][kp] = acc;
        }
        __syncthreads();
        if (tid < 16) {
          float s = 0.f;
          #pragma unroll
          for (int j = 0; j < 8; ++j) s += p0red[tid][j];
          out[((size_t)(b4 * 4 + (tid >> 2)) * T + (t - 1)) * OUTD + a16 * 4 + (tid & 3)]
              = s + bfc[a16 * 4 + (tid & 3)];
        }
      }
    }
    ++seq; gridbar(flags, seq, bid, tid);

    // ---------------- P1: attention ----------------
    {
      const int ba = bid >> 2, s4 = bid & 3;
      const int lane = tid & 63, wv = tid >> 6;
      float q4[4];
      const float* qrow = qbuf + ba * ATTN;
      #pragma unroll
      for (int j = 0; j < 4; ++j) q4[j] = qrow[lane + 64 * j];
      for (int i = 0; i < 8; ++i) {
        const int el = wv * 8 + i;
        const float* krow = keys + ((size_t)(ba * TE) + s4 * 64 + el) * ATTN;
        float p = 0.f;
        #pragma unroll
        for (int j = 0; j < 4; ++j)
          p = fmaf(fast_tanh(q4[j] + krow[lane + 64 * j]), vv4[j], p);
        #pragma unroll
        for (int m = 1; m < 64; m <<= 1) p += __shfl_xor(p, m, 64);
        if (lane == 0) lw[el] = fast_exp(p);
      }
      __syncthreads();
      if (tid < 64) {
        float p = lw[tid];
        #pragma unroll
        for (int m = 1; m < 64; m <<= 1) p += __shfl_xor(p, m, 64);
        if (tid == 0) atomicAdd(denb + (t & 1) * B + ba, p);
      }
      float acc = 0.f;
      const float* erow = enc + ((size_t)(ba * TE) + s4 * 64) * HID + tid;
      #pragma unroll 4
      for (int e = 0; e < 64; ++e) acc = fmaf(lw[e], erow[(size_t)e * HID], acc);
      atomicAdd(ctxb + (size_t)(t & 1) * B * HID + ba * HID + tid, acc);
      // zero next step's accumulators (safe: 2 barriers from both last reader and next writer)
      if (tid < 128) ctxb[(size_t)((t + 1) & 1) * B * HID + ba * HID + s4 * 128 + tid] = 0.f;
      if (s4 == 0 && tid == 0) denb[((t + 1) & 1) * B + ba] = 0.f;
    }
    ++seq; gridbar(flags, seq, bid, tid);

    // ---------------- P2: gates + LSTM update ----------------
    {
      const float* hprev = hbuf + (size_t)(t & 1) * B * HID;
      float* hnext = hbuf + (size_t)((t + 1) & 1) * B * HID;
      const float* ctxcur = ctxb + (size_t)(t & 1) * B * HID;
      if (tid < 16) linv[tid] = 1.0f / denb[(t & 1) * B + bg * 16 + tid];
      __syncthreads();
      for (int cc = 0; cc < 2; ++cc) {
        for (int bb = 0; bb < 8; ++bb) {
          const int bglob = bg * 16 + cc * 8 + bb;
          const float li = linv[cc * 8 + bb];
          for (int k = tid; k < KIN; k += BS) {
            float val;
            if (k < 64)       val = x[((size_t)bglob * T + t) * IN_DIM + k];
            else if (k < 576) val = ctxcur[bglob * HID + (k - 64)] * li;
            else              val = hprev[bglob * HID + (k - 576)];
            ilds[bb][k] = val;
          }
        }
        __syncthreads();
        #pragma unroll
        for (int bb = 0; bb < 8; ++bb) {
          const float* ib = &ilds[bb][ks * 68];
          float a0 = 0.f;
          #pragma unroll
          for (int i = 0; i < 17; ++i) {
            float4 iv = ((const float4*)ib)[i];
            a0 = fmaf(wreg[4 * i + 0], iv.x, a0);
            a0 = fmaf(wreg[4 * i + 1], iv.y, a0);
            a0 = fmaf(wreg[4 * i + 2], iv.z, a0);
            a0 = fmaf(wreg[4 * i + 3], iv.w, a0);
          }
          parts[bb][ks][r_loc] = a0;
        }
        __syncthreads();
        if (tid < 256) {
          const int bbl = tid >> 5, rr = tid & 31;
          float s = blds[rr];
          #pragma unroll
          for (int j = 0; j < 16; ++j) s += parts[bbl][j][rr];
          glds[cc * 8 + bbl][rr] = s;
        }
        __syncthreads();
      }
      if (tid < 128) {
        const int bbl = tid >> 3, hl = tid & 7;
        const int b = bg * 16 + bbl, hu = rg * 8 + hl;
        const float gi = glds[bbl][hl],      gf = glds[bbl][8 + hl];
        const float gg = glds[bbl][16 + hl], go = glds[bbl][24 + hl];
        const float cold = cbuf[b * HID + hu];
        const float cn = fast_sig(gf) * cold + fast_sig(gi) * fast_tanh(gg);
        const float hn = fast_sig(go) * fast_tanh(cn);
        cbuf[b * HID + hu] = cn;
        hnext[b * HID + hu] = hn;
      }
    }
    ++seq; gridbar(flags, seq, bid, tid);
  }

  // ---------------- epilogue: out(127) from h_127 (in hbuf[0]) ----------------
  {
    const float* hprev = hbuf;  // (128 & 1) == 0
    const int b4 = bid >> 4, a16 = bid & 15;
    if (tid < 128) {
      const int d2 = tid >> 3, kp = tid & 7;
      const int ob = b4 * 4 + (d2 >> 2), oo = a16 * 4 + (d2 & 3);
      const float* hr = hprev + ob * HID + kp * 64;
      const float* wr = Wfc + (size_t)oo * HID + kp * 64;
      float acc = 0.f;
      #pragma unroll
      for (int i = 0; i < 16; ++i) {
        float4 h4 = ((const float4*)hr)[i];
        float4 w4 = ((const float4*)wr)[i];
        acc = fmaf(h4.x, w4.x, acc); acc = fmaf(h4.y, w4.y, acc);
        acc = fmaf(h4.z, w4.z, acc); acc = fmaf(h4.w, w4.w, acc);
      }
      p0red[d2][kp] = acc;
    }
    __syncthreads();
    if (tid < 16) {
      float s = 0.f;
      #pragma unroll
      for (int j = 0; j < 8; ++j) s += p0red[tid][j];
      out[((size_t)(b4 * 4 + (tid >> 2)) * T + 127) * OUTD + a16 * 4 + (tid & 3)]
          = s + bfc[a16 * 4 + (tid & 3)];
    }
  }
}

extern "C" void kernel_launch(void* const* d_in, const int* in_sizes, int n_in,
                              void* d_out, int out_size, void* d_ws, size_t ws_size,
                              hipStream_t stream) {
  const float* x   = (const float*)d_in[0];
  const float* enc = (const float*)d_in[1];
  const float* Wq  = (const float*)d_in[2];
  const float* Wk  = (const float*)d_in[3];
  const float* v   = (const float*)d_in[4];
  const float* Wih = (const float*)d_in[5];
  const float* Whh = (const float*)d_in[6];
  const float* bih = (const float*)d_in[7];
  const float* bhh = (const float*)d_in[8];
  const float* Wfc = (const float*)d_in[9];
  const float* bfc = (const float*)d_in[10];

  float* ws   = (float*)d_ws;                 // needs ~17.5 MB
  float* keys = ws;
  float* hbuf = keys + (size_t)B * TE * ATTN; // 2 buffers
  float* cbuf = hbuf + 2 * B * HID;
  float* qbuf = cbuf + B * HID;
  float* ctxb = qbuf + B * ATTN;              // 2 buffers
  float* denb = ctxb + 2 * B * HID;           // 2 buffers
  int*   flags = (int*)(denb + 2 * B);

  keys_kernel<<<dim3(1024), dim3(256), 0, stream>>>(enc, Wk, keys);
  main_kernel<<<dim3(G), dim3(BS), 0, stream>>>(
      x, enc, Wq, v, Wih, Whh, bih, bhh, Wfc, bfc,
      keys, hbuf, cbuf, qbuf, ctxb, denb, flags, (float*)d_out);
}

// Round 2
// 8380.705 us; speedup vs baseline: 3.1125x; 3.1125x over previous
//
#include <hip/hip_runtime.h>

// LSTM decoder w/ Bahdanau attention, MI355X.
// Persistent grid-synchronized kernel, 256 blocks x 512 threads (1 block/CU).
//   keys = enc @ Wk^T precomputed by a separate tiled GEMM kernel.
//   Per step t (3 grid barriers):
//     P0: q(t) = h_{t-1} @ Wq^T  (+ out(t-1) = h_{t-1} @ Wfc^T + b_fc)
//     P1: attention: e = tanh(q+keys)·v, unnormalized softmax (|e|<=13 so exp is fp32-safe),
//         atomicAdd context partials + denominator (4 sub-blocks per batch elem)
//     P2: gates = [x_t, ctx, h] @ [Wih|Whh]^T + bias; LSTM pointwise; h/c update.
//         Gate weights persistent in REGISTERS (68 fp32/thread), inputs broadcast from LDS.
//
// R1 lesson: __threadfence/acquire => buffer_wbl2/buffer_inv (full L2 flush) per op on
// gfx950 => 65us/barrier. Fix: ALL cross-block mutable data via RELAXED agent-scope
// atomics (sc1, cache-bypassing, no cache maintenance); barrier = s_waitcnt vmcnt(0) +
// relaxed flag store + relaxed poll. Read-only tensors stay normally cached in L2.

#define B 64
#define T 128
#define IN_DIM 64
#define TE 256
#define HID 512
#define ATTN 256
#define OUTD 64
#define KIN 1088   // 576 (x,ctx) + 512 (h)
#define G 256      // main grid blocks
#define BS 512     // main block threads

__device__ __forceinline__ float fast_exp(float x) {
  return __builtin_amdgcn_exp2f(x * 1.44269504f);
}
__device__ __forceinline__ float fast_tanh(float x) {
  float ax = fabsf(x);
  float z = __builtin_amdgcn_exp2f(ax * -2.885390082f);  // e^{-2|x|}
  float r = (1.f - z) * __builtin_amdgcn_rcpf(1.f + z);
  return copysignf(r, x);
}
__device__ __forceinline__ float fast_sig(float x) {
  float z = __builtin_amdgcn_exp2f(x * -1.44269504f);    // e^{-x}
  return __builtin_amdgcn_rcpf(1.f + z);
}

// Relaxed agent-scope atomics: compile to global_load/store ... sc1 (bypass
// non-coherent L1/L2, complete at coherence point). NO buffer_wbl2 / buffer_inv.
__device__ __forceinline__ float ald(const float* p) {
  return __hip_atomic_load((float*)p, __ATOMIC_RELAXED, __HIP_MEMORY_SCOPE_AGENT);
}
__device__ __forceinline__ void ast(float* p, float v) {
  __hip_atomic_store(p, v, __ATOMIC_RELAXED, __HIP_MEMORY_SCOPE_AGENT);
}

// Barrier: every wave drains its own VMEM (acks at coherence point for sc1 ops),
// s_barrier joins the block, tid0 publishes seq, one wave polls all 256 flags.
// Signed >= compare: the 0xAA ws-poison is negative as int32 -> never false-passes.
__device__ __forceinline__ void gridbar(int* flags, int seq, int bid, int tid) {
  asm volatile("s_waitcnt vmcnt(0)" ::: "memory");
  __syncthreads();
  if (tid == 0)
    __hip_atomic_store(&flags[bid], seq, __ATOMIC_RELAXED, __HIP_MEMORY_SCOPE_AGENT);
  if (tid < 64) {
    #pragma unroll
    for (int j = 0; j < 4; ++j) {
      while (__hip_atomic_load(&flags[tid + 64 * j], __ATOMIC_RELAXED,
                               __HIP_MEMORY_SCOPE_AGENT) < seq) {
        __builtin_amdgcn_s_sleep(4);
      }
    }
  }
  __syncthreads();
}

// ---- keys[b][e][a] = sum_k enc[b][e][k] * Wk[a][k] ----
// grid: 64 b * 16 e-tiles = 1024 blocks, 256 threads.
__global__ __launch_bounds__(256, 2) void keys_kernel(
    const float* __restrict__ enc, const float* __restrict__ Wk,
    float* __restrict__ keys) {
  __shared__ float et[16][512];   // enc tile, full K
  __shared__ float wk[32][256];   // k-major Wk chunk
  const int tid = threadIdx.x;
  const int b = blockIdx.x >> 4;
  const int e0 = (blockIdx.x & 15) * 16;

  for (int p = 0; p < 8; ++p) {
    int i = p * 256 + tid;
    int e = i >> 7, kq = i & 127;
    float4 vv = *(const float4*)&enc[((size_t)(b * TE + e0 + e)) * HID + kq * 4];
    *(float4*)&et[e][kq * 4] = vv;
  }

  float acc[8][2];
  #pragma unroll
  for (int i = 0; i < 8; ++i) { acc[i][0] = 0.f; acc[i][1] = 0.f; }
  const int a0 = tid & 127;
  const int eh = (tid >> 7) * 8;

  for (int kc = 0; kc < 512; kc += 32) {
    __syncthreads();
    for (int p = 0; p < 8; ++p) {
      int i = p * 256 + tid;
      int a = i >> 3, j4 = (i & 7) * 4;
      float4 w4 = *(const float4*)&Wk[(size_t)a * HID + kc + j4];
      wk[j4 + 0][a] = w4.x; wk[j4 + 1][a] = w4.y;
      wk[j4 + 2][a] = w4.z; wk[j4 + 3][a] = w4.w;
    }
    __syncthreads();
    for (int k = 0; k < 32; ++k) {
      float w0 = wk[k][a0], w1 = wk[k][a0 + 128];
      #pragma unroll
      for (int i = 0; i < 8; ++i) {
        float ev = et[eh + i][kc + k];
        acc[i][0] = fmaf(ev, w0, acc[i][0]);
        acc[i][1] = fmaf(ev, w1, acc[i][1]);
      }
    }
  }
  #pragma unroll
  for (int i = 0; i < 8; ++i) {
    keys[((size_t)(b * TE + e0 + eh + i)) * ATTN + a0] = acc[i][0];
    keys[((size_t)(b * TE + e0 + eh + i)) * ATTN + a0 + 128] = acc[i][1];
  }
}

__global__ __launch_bounds__(BS, 2) void main_kernel(
    const float* __restrict__ x, const float* __restrict__ enc,
    const float* __restrict__ Wq, const float* __restrict__ v,
    const float* __restrict__ Wih, const float* __restrict__ Whh,
    const float* __restrict__ bih, const float* __restrict__ bhh,
    const float* __restrict__ Wfc, const float* __restrict__ bfc,
    const float* __restrict__ keys,
    float* hbuf, float* cbuf, float* qbuf, float* ctxb, float* denb,
    int* flags, float* out) {
  const int bid = blockIdx.x, tid = threadIdx.x;

  // P2 role: rg = hidden-slice [rg*8,+8), bg = batch group [bg*16,+16)
  const int rg = bid >> 2;
  const int bg = bid & 3;
  const int r_loc = tid & 31;               // row-local: gate = r>>3, hu = r&7
  const int ks = tid >> 5;                  // k-slice [ks*68, +68)
  const int grow = (r_loc >> 3) * 512 + rg * 8 + (r_loc & 7);  // global gate row

  __shared__ float ilds[8][KIN];            // 34.8 KB staged inputs (8 batch) [P2]
  __shared__ float parts[8][16][33];        // 16.9 KB dot partials [bb][ks][r]
  __shared__ float glds[16][32];            // gate values [bb16][r]
  __shared__ float lw[64];                  // P1 exp weights
  __shared__ float p0red[64][9];            // P0 reduce scratch
  __shared__ float blds[32];                // biases for this block's rows
  __shared__ float linv[16];                // 1/den per batch in group
  // P0 h staging aliases ilds (phases are barrier-separated)
  float (*hlds)[HID] = (float(*)[HID]) & ilds[0][0];  // [4][512]

  // ---- prologue: persistent weight registers, biases, v, zero state ----
  float wreg[68];
  #pragma unroll
  for (int i = 0; i < 68; ++i) {
    const int k = ks * 68 + i;
    wreg[i] = (k < 576) ? Wih[(size_t)grow * 576 + k]
                        : Whh[(size_t)grow * 512 + (k - 576)];
  }
  if (tid < 32) {
    const int gr2 = (tid >> 3) * 512 + rg * 8 + (tid & 7);
    blds[tid] = bih[gr2] + bhh[gr2];
  }
  float vv4[4];
  {
    const int lane = tid & 63;
    #pragma unroll
    for (int j = 0; j < 4; ++j) vv4[j] = v[lane + 64 * j];
  }
  // zero [hbuf(2) | cbuf | qbuf | ctxb(2) | den(2)] = 180352 floats (fabric stores:
  // plain stores would leave dirty lines invisible to other blocks' sc1 loads)
  for (int i = bid * BS + tid; i < 180352; i += G * BS) ast(hbuf + i, 0.f);

  int seq = 1;
  gridbar(flags, seq, bid, tid);

  for (int t = 0; t < T; ++t) {
    // ---------------- P0: q(t) and out(t-1) ----------------
    {
      const float* hprev = hbuf + (size_t)(t & 1) * B * HID;
      const int b4 = bid >> 4, a16 = bid & 15;
      // stage this block's 4 batches of h into LDS (coalesced fabric loads)
      for (int i = tid; i < 4 * HID; i += BS)
        hlds[i >> 9][i & 511] = ald(hprev + (b4 * 4 + (i >> 9)) * HID + (i & 511));
      __syncthreads();
      {
        const int d = tid >> 3, kp = tid & 7;
        const int qb = d >> 4, qa = a16 * 16 + (d & 15);
        const float* hr = &hlds[qb][kp * 64];
        const float* wr = Wq + (size_t)qa * HID + kp * 64;
        float acc = 0.f;
        #pragma unroll
        for (int i = 0; i < 16; ++i) {
          float4 h4 = ((const float4*)hr)[i];
          float4 w4 = ((const float4*)wr)[i];
          acc = fmaf(h4.x, w4.x, acc); acc = fmaf(h4.y, w4.y, acc);
          acc = fmaf(h4.z, w4.z, acc); acc = fmaf(h4.w, w4.w, acc);
        }
        p0red[d][kp] = acc;
      }
      __syncthreads();
      if (tid < 64) {
        float s = 0.f;
        #pragma unroll
        for (int j = 0; j < 8; ++j) s += p0red[tid][j];
        ast(qbuf + (b4 * 4 + (tid >> 4)) * ATTN + a16 * 16 + (tid & 15), s);
      }
      if (t >= 1) {
        __syncthreads();
        if (tid < 128) {
          const int d2 = tid >> 3, kp = tid & 7;
          const int ob = d2 >> 2, oo = a16 * 4 + (d2 & 3);
          const float* hr = &hlds[ob][kp * 64];
          const float* wr = Wfc + (size_t)oo * HID + kp * 64;
          float acc = 0.f;
          #pragma unroll
          for (int i = 0; i < 16; ++i) {
            float4 h4 = ((const float4*)hr)[i];
            float4 w4 = ((const float4*)wr)[i];
            acc = fmaf(h4.x, w4.x, acc); acc = fmaf(h4.y, w4.y, acc);
            acc = fmaf(h4.z, w4.z, acc); acc = fmaf(h4.w, w4.w, acc);
          }
          p0red[d2][kp] = acc;
        }
        __syncthreads();
        if (tid < 16) {
          float s = 0.f;
          #pragma unroll
          for (int j = 0; j < 8; ++j) s += p0red[tid][j];
          out[((size_t)(b4 * 4 + (tid >> 2)) * T + (t - 1)) * OUTD + a16 * 4 + (tid & 3)]
              = s + bfc[a16 * 4 + (tid & 3)];
        }
      }
    }
    ++seq; gridbar(flags, seq, bid, tid);

    // ---------------- P1: attention ----------------
    {
      const int ba = bid >> 2, s4 = bid & 3;
      const int lane = tid & 63, wv = tid >> 6;
      float q4[4];
      const float* qrow = qbuf + ba * ATTN;
      #pragma unroll
      for (int j = 0; j < 4; ++j) q4[j] = ald(qrow + lane + 64 * j);
      for (int i = 0; i < 8; ++i) {
        const int el = wv * 8 + i;
        const float* krow = keys + ((size_t)(ba * TE) + s4 * 64 + el) * ATTN;
        float p = 0.f;
        #pragma unroll
        for (int j = 0; j < 4; ++j)
          p = fmaf(fast_tanh(q4[j] + krow[lane + 64 * j]), vv4[j], p);
        #pragma unroll
        for (int m = 1; m < 64; m <<= 1) p += __shfl_xor(p, m, 64);
        if (lane == 0) lw[el] = fast_exp(p);
      }
      __syncthreads();
      if (tid < 64) {
        float p = lw[tid];
        #pragma unroll
        for (int m = 1; m < 64; m <<= 1) p += __shfl_xor(p, m, 64);
        if (tid == 0) atomicAdd(denb + (t & 1) * B + ba, p);
      }
      float acc = 0.f;
      const float* erow = enc + ((size_t)(ba * TE) + s4 * 64) * HID + tid;
      #pragma unroll 4
      for (int e = 0; e < 64; ++e) acc = fmaf(lw[e], erow[(size_t)e * HID], acc);
      atomicAdd(ctxb + (size_t)(t & 1) * B * HID + ba * HID + tid, acc);
      // zero next step's accumulators (2 barriers from both last reader and next writer)
      if (tid < 128)
        ast(ctxb + (size_t)((t + 1) & 1) * B * HID + ba * HID + s4 * 128 + tid, 0.f);
      if (s4 == 0 && tid == 0) ast(denb + ((t + 1) & 1) * B + ba, 0.f);
    }
    ++seq; gridbar(flags, seq, bid, tid);

    // ---------------- P2: gates + LSTM update ----------------
    {
      const float* hprev = hbuf + (size_t)(t & 1) * B * HID;
      float* hnext = hbuf + (size_t)((t + 1) & 1) * B * HID;
      const float* ctxcur = ctxb + (size_t)(t & 1) * B * HID;
      if (tid < 16) linv[tid] = 1.0f / ald(denb + (t & 1) * B + bg * 16 + tid);
      __syncthreads();
      for (int cc = 0; cc < 2; ++cc) {
        for (int bb = 0; bb < 8; ++bb) {
          const int bglob = bg * 16 + cc * 8 + bb;
          const float li = linv[cc * 8 + bb];
          for (int k = tid; k < KIN; k += BS) {
            float val;
            if (k < 64)       val = x[((size_t)bglob * T + t) * IN_DIM + k];
            else if (k < 576) val = ald(ctxcur + bglob * HID + (k - 64)) * li;
            else              val = ald(hprev + bglob * HID + (k - 576));
            ilds[bb][k] = val;
          }
        }
        __syncthreads();
        #pragma unroll
        for (int bb = 0; bb < 8; ++bb) {
          const float* ib = &ilds[bb][ks * 68];
          float a0 = 0.f;
          #pragma unroll
          for (int i = 0; i < 17; ++i) {
            float4 iv = ((const float4*)ib)[i];
            a0 = fmaf(wreg[4 * i + 0], iv.x, a0);
            a0 = fmaf(wreg[4 * i + 1], iv.y, a0);
            a0 = fmaf(wreg[4 * i + 2], iv.z, a0);
            a0 = fmaf(wreg[4 * i + 3], iv.w, a0);
          }
          parts[bb][ks][r_loc] = a0;
        }
        __syncthreads();
        if (tid < 256) {
          const int bbl = tid >> 5, rr = tid & 31;
          float s = blds[rr];
          #pragma unroll
          for (int j = 0; j < 16; ++j) s += parts[bbl][j][rr];
          glds[cc * 8 + bbl][rr] = s;
        }
        __syncthreads();
      }
      if (tid < 128) {
        const int bbl = tid >> 3, hl = tid & 7;
        const int b = bg * 16 + bbl, hu = rg * 8 + hl;
        const float gi = glds[bbl][hl],      gf = glds[bbl][8 + hl];
        const float gg = glds[bbl][16 + hl], go = glds[bbl][24 + hl];
        const float cold = cbuf[b * HID + hu];  // block-private: plain cached ok
        const float cn = fast_sig(gf) * cold + fast_sig(gi) * fast_tanh(gg);
        const float hn = fast_sig(go) * fast_tanh(cn);
        cbuf[b * HID + hu] = cn;
        ast(&hnext[b * HID + hu], hn);
      }
    }
    ++seq; gridbar(flags, seq, bid, tid);
  }

  // ---------------- epilogue: out(127) from h_127 (in hbuf[0]) ----------------
  {
    const float* hprev = hbuf;  // (128 & 1) == 0
    const int b4 = bid >> 4, a16 = bid & 15;
    for (int i = tid; i < 4 * HID; i += BS)
      hlds[i >> 9][i & 511] = ald(hprev + (b4 * 4 + (i >> 9)) * HID + (i & 511));
    __syncthreads();
    if (tid < 128) {
      const int d2 = tid >> 3, kp = tid & 7;
      const int ob = d2 >> 2, oo = a16 * 4 + (d2 & 3);
      const float* hr = &hlds[ob][kp * 64];
      const float* wr = Wfc + (size_t)oo * HID + kp * 64;
      float acc = 0.f;
      #pragma unroll
      for (int i = 0; i < 16; ++i) {
        float4 h4 = ((const float4*)hr)[i];
        float4 w4 = ((const float4*)wr)[i];
        acc = fmaf(h4.x, w4.x, acc); acc = fmaf(h4.y, w4.y, acc);
        acc = fmaf(h4.z, w4.z, acc); acc = fmaf(h4.w, w4.w, acc);
      }
      p0red[d2][kp] = acc;
    }
    __syncthreads();
    if (tid < 16) {
      float s = 0.f;
      #pragma unroll
      for (int j = 0; j < 8; ++j) s += p0red[tid][j];
      out[((size_t)(b4 * 4 + (tid >> 2)) * T + 127) * OUTD + a16 * 4 + (tid & 3)]
          = s + bfc[a16 * 4 + (tid & 3)];
    }
  }
}

extern "C" void kernel_launch(void* const* d_in, const int* in_sizes, int n_in,
                              void* d_out, int out_size, void* d_ws, size_t ws_size,
                              hipStream_t stream) {
  const float* x   = (const float*)d_in[0];
  const float* enc = (const float*)d_in[1];
  const float* Wq  = (const float*)d_in[2];
  const float* Wk  = (const float*)d_in[3];
  const float* v   = (const float*)d_in[4];
  const float* Wih = (const float*)d_in[5];
  const float* Whh = (const float*)d_in[6];
  const float* bih = (const float*)d_in[7];
  const float* bhh = (const float*)d_in[8];
  const float* Wfc = (const float*)d_in[9];
  const float* bfc = (const float*)d_in[10];

  float* ws   = (float*)d_ws;                 // needs ~17.5 MB
  float* keys = ws;
  float* hbuf = keys + (size_t)B * TE * ATTN; // 2 buffers
  float* cbuf = hbuf + 2 * B * HID;
  float* qbuf = cbuf + B * HID;
  float* ctxb = qbuf + B * ATTN;              // 2 buffers
  float* denb = ctxb + 2 * B * HID;           // 2 buffers
  int*   flags = (int*)(denb + 2 * B);

  keys_kernel<<<dim3(1024), dim3(256), 0, stream>>>(enc, Wk, keys);
  main_kernel<<<dim3(G), dim3(BS), 0, stream>>>(
      x, enc, Wq, v, Wih, Whh, bih, bhh, Wfc, bfc,
      keys, hbuf, cbuf, qbuf, ctxb, denb, flags, (float*)d_out);
}

// Round 3
// 7249.816 us; speedup vs baseline: 3.5981x; 1.1560x over previous
//
#include <hip/hip_runtime.h>

// LSTM decoder w/ Bahdanau attention, MI355X.
// Persistent grid-synchronized kernel, 256 blocks x 512 threads (1 block/CU).
//   keys = enc @ Wk^T precomputed by a separate tiled GEMM kernel.
//   Per step t (3 grid barriers):
//     P0: stage h -> LDS; q(t) = h_{t-1} @ Wq^T (wave-local shuffle reduce, no LDS scratch)
//     P1: preload keys->regs; out(t-1)=h@Wfc^T in the load shadow; energies+softmax;
//         context partials via atomicAdd (4 sub-blocks per batch elem)
//     P2: gates = [x_t, ctx, h] @ [Wih|Whh]^T + bias; LSTM pointwise; h/c update.
//         Gate weights persistent in REGISTERS (68 fp32/thread), inputs broadcast from LDS.
//
// R1 lesson: __threadfence/acquire => buffer_wbl2/buffer_inv (L2 flush) per op => 65us
//   barriers. All cross-block mutable data via RELAXED agent-scope atomics (sc1).
// R2 lesson: (a) hlds reads at kp*64 stride = 8-way bank conflict (1.5e8 cycles) -> lane
//   k-chunks now (lane&31)*4+128i (bank==lane quad, conflict-free). (b) latency-bound
//   phases (VALUBusy 12%): preload keys to regs, unroll ctx loop 32-wide, wave-local
//   reductions to drop vmcnt-draining __syncthreads, parallel rcp(den) loads in P2.

#define B 64
#define T 128
#define IN_DIM 64
#define TE 256
#define HID 512
#define ATTN 256
#define OUTD 64
#define KIN 1088   // 64 (x) + 512 (ctx) + 512 (h)
#define G 256      // main grid blocks
#define BS 512     // main block threads

__device__ __forceinline__ float fast_exp(float x) {
  return __builtin_amdgcn_exp2f(x * 1.44269504f);
}
__device__ __forceinline__ float fast_tanh(float x) {
  float ax = fabsf(x);
  float z = __builtin_amdgcn_exp2f(ax * -2.885390082f);  // e^{-2|x|}
  float r = (1.f - z) * __builtin_amdgcn_rcpf(1.f + z);
  return copysignf(r, x);
}
__device__ __forceinline__ float fast_sig(float x) {
  float z = __builtin_amdgcn_exp2f(x * -1.44269504f);    // e^{-x}
  return __builtin_amdgcn_rcpf(1.f + z);
}

// Relaxed agent-scope atomics: global_load/store ... sc1 (coherence point, no L2 flush).
__device__ __forceinline__ float ald(const float* p) {
  return __hip_atomic_load((float*)p, __ATOMIC_RELAXED, __HIP_MEMORY_SCOPE_AGENT);
}
__device__ __forceinline__ void ast(float* p, float v) {
  __hip_atomic_store(p, v, __ATOMIC_RELAXED, __HIP_MEMORY_SCOPE_AGENT);
}

// Barrier: drain own VMEM, block-join, publish seq, one wave polls all 256 flags.
// Signed >= compare: 0xAA ws-poison is negative as int32 -> never false-passes.
__device__ __forceinline__ void gridbar(int* flags, int seq, int bid, int tid) {
  asm volatile("s_waitcnt vmcnt(0)" ::: "memory");
  __syncthreads();
  if (tid == 0)
    __hip_atomic_store(&flags[bid], seq, __ATOMIC_RELAXED, __HIP_MEMORY_SCOPE_AGENT);
  if (tid < 64) {
    #pragma unroll
    for (int j = 0; j < 4; ++j) {
      while (__hip_atomic_load(&flags[tid + 64 * j], __ATOMIC_RELAXED,
                               __HIP_MEMORY_SCOPE_AGENT) < seq) {
        __builtin_amdgcn_s_sleep(4);
      }
    }
  }
  __syncthreads();
}

// ---- keys[b][e][a] = sum_k enc[b][e][k] * Wk[a][k] ----
__global__ __launch_bounds__(256, 2) void keys_kernel(
    const float* __restrict__ enc, const float* __restrict__ Wk,
    float* __restrict__ keys) {
  __shared__ float et[16][512];
  __shared__ float wk[32][256];
  const int tid = threadIdx.x;
  const int b = blockIdx.x >> 4;
  const int e0 = (blockIdx.x & 15) * 16;

  for (int p = 0; p < 8; ++p) {
    int i = p * 256 + tid;
    int e = i >> 7, kq = i & 127;
    float4 vv = *(const float4*)&enc[((size_t)(b * TE + e0 + e)) * HID + kq * 4];
    *(float4*)&et[e][kq * 4] = vv;
  }

  float acc[8][2];
  #pragma unroll
  for (int i = 0; i < 8; ++i) { acc[i][0] = 0.f; acc[i][1] = 0.f; }
  const int a0 = tid & 127;
  const int eh = (tid >> 7) * 8;

  for (int kc = 0; kc < 512; kc += 32) {
    __syncthreads();
    for (int p = 0; p < 8; ++p) {
      int i = p * 256 + tid;
      int a = i >> 3, j4 = (i & 7) * 4;
      float4 w4 = *(const float4*)&Wk[(size_t)a * HID + kc + j4];
      wk[j4 + 0][a] = w4.x; wk[j4 + 1][a] = w4.y;
      wk[j4 + 2][a] = w4.z; wk[j4 + 3][a] = w4.w;
    }
    __syncthreads();
    for (int k = 0; k < 32; ++k) {
      float w0 = wk[k][a0], w1 = wk[k][a0 + 128];
      #pragma unroll
      for (int i = 0; i < 8; ++i) {
        float ev = et[eh + i][kc + k];
        acc[i][0] = fmaf(ev, w0, acc[i][0]);
        acc[i][1] = fmaf(ev, w1, acc[i][1]);
      }
    }
  }
  #pragma unroll
  for (int i = 0; i < 8; ++i) {
    keys[((size_t)(b * TE + e0 + eh + i)) * ATTN + a0] = acc[i][0];
    keys[((size_t)(b * TE + e0 + eh + i)) * ATTN + a0 + 128] = acc[i][1];
  }
}

__global__ __launch_bounds__(BS, 2) void main_kernel(
    const float* __restrict__ x, const float* __restrict__ enc,
    const float* __restrict__ Wq, const float* __restrict__ v,
    const float* __restrict__ Wih, const float* __restrict__ Whh,
    const float* __restrict__ bih, const float* __restrict__ bhh,
    const float* __restrict__ Wfc, const float* __restrict__ bfc,
    const float* __restrict__ keys,
    float* hbuf, float* cbuf, float* qbuf, float* ctxb, float* denb,
    int* flags, float* out) {
  const int bid = blockIdx.x, tid = threadIdx.x;

  // P2 role: rg = hidden-slice [rg*8,+8), bg = batch group [bg*16,+16)
  const int rg = bid >> 2;
  const int bg = bid & 3;
  const int r_loc = tid & 31;               // row-local: gate = r>>3, hu = r&7
  const int ks = tid >> 5;                  // k-slice [ks*68, +68)
  const int grow = (r_loc >> 3) * 512 + rg * 8 + (r_loc & 7);
  // P0/P1 role: b4/a16 (h tiles); P1: ba/s4 (attention)
  const int b4 = bid >> 4, a16 = bid & 15;
  const int ba = bid >> 2, s4 = bid & 3;
  const int lane = tid & 63, wv = tid >> 6;
  const int hw = tid >> 5, lb = tid & 31;   // half-wave id / lane-in-half

  __shared__ float ilds[8][KIN];            // 34.8 KB staged inputs (8 batch) [P2]
  __shared__ float parts[8][16][33];        // 16.9 KB dot partials [bb][ks][r]
  __shared__ float glds[16][32];            // gate values [bb16][r]
  __shared__ float lw[64];                  // P1 exp weights
  __shared__ float blds[32];                // biases for this block's rows
  // P0/P1 h staging aliases ilds (phases are barrier-separated; P2 re-stages ilds)
  float (*hlds)[HID] = (float(*)[HID]) & ilds[0][0];  // [4][512]

  // ---- prologue ----
  float wreg[68];
  #pragma unroll
  for (int i = 0; i < 68; ++i) {
    const int k = ks * 68 + i;
    wreg[i] = (k < 576) ? Wih[(size_t)grow * 576 + k]
                        : Whh[(size_t)grow * 512 + (k - 576)];
  }
  if (tid < 32) {
    const int gr2 = (tid >> 3) * 512 + rg * 8 + (tid & 7);
    blds[tid] = bih[gr2] + bhh[gr2];
  }
  float vv4[4];
  #pragma unroll
  for (int j = 0; j < 4; ++j) vv4[j] = v[lane + 64 * j];
  // zero [hbuf(2) | cbuf | qbuf | ctxb(2) | den(2)] = 180352 floats (fabric stores)
  for (int i = bid * BS + tid; i < 180352; i += G * BS) ast(hbuf + i, 0.f);

  int seq = 1;
  gridbar(flags, seq, bid, tid);

  for (int t = 0; t < T; ++t) {
    // ---------------- P0: stage h, q(t) wave-local ----------------
    {
      const float* hprev = hbuf + (size_t)(t & 1) * B * HID;
      #pragma unroll
      for (int i = tid; i < 4 * HID; i += BS)
        hlds[i >> 9][i & 511] = ald(hprev + (b4 * 4 + (i >> 9)) * HID + (i & 511));
      __syncthreads();
      // q-values: half-wave hw owns v = hw*4+j; lane k-chunk = lb*4 + 128i (bank==lane)
      #pragma unroll
      for (int j = 0; j < 4; ++j) {
        const int vq = hw * 4 + j;
        const int qb = vq >> 4, qa = a16 * 16 + (vq & 15);
        const float* wr = Wq + (size_t)qa * HID + lb * 4;
        const float* hr = &hlds[qb][lb * 4];
        float acc = 0.f;
        #pragma unroll
        for (int i = 0; i < 4; ++i) {
          float4 h4 = *(const float4*)(hr + i * 128);
          float4 w4 = *(const float4*)(wr + i * 128);
          acc = fmaf(h4.x, w4.x, acc); acc = fmaf(h4.y, w4.y, acc);
          acc = fmaf(h4.z, w4.z, acc); acc = fmaf(h4.w, w4.w, acc);
        }
        #pragma unroll
        for (int m = 1; m < 32; m <<= 1) acc += __shfl_xor(acc, m, 64);
        if (lb == 0) ast(qbuf + (b4 * 4 + qb) * ATTN + qa, acc);
      }
    }
    ++seq; gridbar(flags, seq, bid, tid);

    // ---------------- P1: attention (+ out(t-1) in the load shadow) ----------------
    {
      // preload this wave's 8 key rows into registers (32 independent loads)
      float kk[8][4];
      #pragma unroll
      for (int i = 0; i < 8; ++i) {
        const float* krow = keys + ((size_t)(ba * TE) + s4 * 64 + wv * 8 + i) * ATTN;
        #pragma unroll
        for (int j = 0; j < 4; ++j) kk[i][j] = krow[lane + 64 * j];
      }
      float q4[4];
      const float* qrow = qbuf + ba * ATTN;
      #pragma unroll
      for (int j = 0; j < 4; ++j) q4[j] = ald(qrow + lane + 64 * j);

      // out(t-1) = h_{t-1} @ Wfc^T + b_fc, wave-local (hlds still valid from P0)
      if (t >= 1) {
        const int ob = hw >> 2, oo = hw & 3;
        const float* wr = Wfc + (size_t)(a16 * 4 + oo) * HID + lb * 4;
        const float* hr = &hlds[ob][lb * 4];
        float acc = 0.f;
        #pragma unroll
        for (int i = 0; i < 4; ++i) {
          float4 h4 = *(const float4*)(hr + i * 128);
          float4 w4 = *(const float4*)(wr + i * 128);
          acc = fmaf(h4.x, w4.x, acc); acc = fmaf(h4.y, w4.y, acc);
          acc = fmaf(h4.z, w4.z, acc); acc = fmaf(h4.w, w4.w, acc);
        }
        #pragma unroll
        for (int m = 1; m < 32; m <<= 1) acc += __shfl_xor(acc, m, 64);
        if (lb == 0)
          out[((size_t)(b4 * 4 + ob) * T + (t - 1)) * OUTD + a16 * 4 + oo]
              = acc + bfc[a16 * 4 + oo];
      }

      // energies -> lw
      #pragma unroll
      for (int i = 0; i < 8; ++i) {
        float p = 0.f;
        #pragma unroll
        for (int j = 0; j < 4; ++j)
          p = fmaf(fast_tanh(q4[j] + kk[i][j]), vv4[j], p);
        #pragma unroll
        for (int m = 1; m < 64; m <<= 1) p += __shfl_xor(p, m, 64);
        if (lane == 0) lw[wv * 8 + i] = fast_exp(p);
      }
      __syncthreads();
      if (tid < 64) {
        float p = lw[tid];
        #pragma unroll
        for (int m = 1; m < 64; m <<= 1) p += __shfl_xor(p, m, 64);
        if (tid == 0) atomicAdd(denb + (t & 1) * B + ba, p);
      }
      // zero next step's accumulators (2 barriers from last reader & next writer)
      if (tid < 128)
        ast(ctxb + (size_t)((t + 1) & 1) * B * HID + ba * HID + s4 * 128 + tid, 0.f);
      if (s4 == 0 && tid == 0) ast(denb + ((t + 1) & 1) * B + ba, 0.f);
      // context: 64 rows, 32 loads in flight
      float acc0 = 0.f, acc1 = 0.f;
      const float* erow = enc + ((size_t)(ba * TE) + s4 * 64) * HID + tid;
      #pragma unroll 16
      for (int e = 0; e < 64; e += 2) {
        acc0 = fmaf(lw[e],     erow[(size_t)e * HID],       acc0);
        acc1 = fmaf(lw[e + 1], erow[(size_t)(e + 1) * HID], acc1);
      }
      atomicAdd(ctxb + (size_t)(t & 1) * B * HID + ba * HID + tid, acc0 + acc1);
    }
    ++seq; gridbar(flags, seq, bid, tid);

    // ---------------- P2: gates + LSTM update ----------------
    {
      const float* hprev = hbuf + (size_t)(t & 1) * B * HID;
      float* hnext = hbuf + (size_t)((t + 1) & 1) * B * HID;
      const float* ctxcur = ctxb + (size_t)(t & 1) * B * HID;
      for (int cc = 0; cc < 2; ++cc) {
        float li[8];
        #pragma unroll
        for (int bb = 0; bb < 8; ++bb)
          li[bb] = __builtin_amdgcn_rcpf(
              ald(denb + (t & 1) * B + bg * 16 + cc * 8 + bb));
        #pragma unroll
        for (int bb = 0; bb < 8; ++bb) {
          const int bglob = bg * 16 + cc * 8 + bb;
          #pragma unroll
          for (int k = tid; k < KIN; k += BS) {
            float val;
            if (k < 64)       val = x[((size_t)bglob * T + t) * IN_DIM + k];
            else if (k < 576) val = ald(ctxcur + bglob * HID + (k - 64)) * li[bb];
            else              val = ald(hprev + bglob * HID + (k - 576));
            ilds[bb][k] = val;
          }
        }
        __syncthreads();
        #pragma unroll
        for (int bb = 0; bb < 8; ++bb) {
          const float* ib = &ilds[bb][ks * 68];
          float a0 = 0.f;
          #pragma unroll
          for (int i = 0; i < 17; ++i) {
            float4 iv = ((const float4*)ib)[i];
            a0 = fmaf(wreg[4 * i + 0], iv.x, a0);
            a0 = fmaf(wreg[4 * i + 1], iv.y, a0);
            a0 = fmaf(wreg[4 * i + 2], iv.z, a0);
            a0 = fmaf(wreg[4 * i + 3], iv.w, a0);
          }
          parts[bb][ks][r_loc] = a0;
        }
        __syncthreads();
        if (tid < 256) {
          const int bbl = tid >> 5, rr = tid & 31;
          float s = blds[rr];
          #pragma unroll
          for (int j = 0; j < 16; ++j) s += parts[bbl][j][rr];
          glds[cc * 8 + bbl][rr] = s;
        }
        __syncthreads();
      }
      if (tid < 128) {
        const int bbl = tid >> 3, hl = tid & 7;
        const int b = bg * 16 + bbl, hu = rg * 8 + hl;
        const float gi = glds[bbl][hl],      gf = glds[bbl][8 + hl];
        const float gg = glds[bbl][16 + hl], go = glds[bbl][24 + hl];
        const float cold = cbuf[b * HID + hu];  // block-private: plain cached ok
        const float cn = fast_sig(gf) * cold + fast_sig(gi) * fast_tanh(gg);
        const float hn = fast_sig(go) * fast_tanh(cn);
        cbuf[b * HID + hu] = cn;
        ast(&hnext[b * HID + hu], hn);
      }
    }
    ++seq; gridbar(flags, seq, bid, tid);
  }

  // ---------------- epilogue: out(127) from h_127 (in hbuf[0]) ----------------
  {
    const float* hprev = hbuf;  // (128 & 1) == 0
    #pragma unroll
    for (int i = tid; i < 4 * HID; i += BS)
      hlds[i >> 9][i & 511] = ald(hprev + (b4 * 4 + (i >> 9)) * HID + (i & 511));
    __syncthreads();
    const int ob = hw >> 2, oo = hw & 3;
    const float* wr = Wfc + (size_t)(a16 * 4 + oo) * HID + lb * 4;
    const float* hr = &hlds[ob][lb * 4];
    float acc = 0.f;
    #pragma unroll
    for (int i = 0; i < 4; ++i) {
      float4 h4 = *(const float4*)(hr + i * 128);
      float4 w4 = *(const float4*)(wr + i * 128);
      acc = fmaf(h4.x, w4.x, acc); acc = fmaf(h4.y, w4.y, acc);
      acc = fmaf(h4.z, w4.z, acc); acc = fmaf(h4.w, w4.w, acc);
    }
    #pragma unroll
    for (int m = 1; m < 32; m <<= 1) acc += __shfl_xor(acc, m, 64);
    if (lb == 0)
      out[((size_t)(b4 * 4 + ob) * T + 127) * OUTD + a16 * 4 + oo]
          = acc + bfc[a16 * 4 + oo];
  }
}

extern "C" void kernel_launch(void* const* d_in, const int* in_sizes, int n_in,
                              void* d_out, int out_size, void* d_ws, size_t ws_size,
                              hipStream_t stream) {
  const float* x   = (const float*)d_in[0];
  const float* enc = (const float*)d_in[1];
  const float* Wq  = (const float*)d_in[2];
  const float* Wk  = (const float*)d_in[3];
  const float* v   = (const float*)d_in[4];
  const float* Wih = (const float*)d_in[5];
  const float* Whh = (const float*)d_in[6];
  const float* bih = (const float*)d_in[7];
  const float* bhh = (const float*)d_in[8];
  const float* Wfc = (const float*)d_in[9];
  const float* bfc = (const float*)d_in[10];

  float* ws   = (float*)d_ws;                 // needs ~17.5 MB
  float* keys = ws;
  float* hbuf = keys + (size_t)B * TE * ATTN; // 2 buffers
  float* cbuf = hbuf + 2 * B * HID;
  float* qbuf = cbuf + B * HID;
  float* ctxb = qbuf + B * ATTN;              // 2 buffers
  float* denb = ctxb + 2 * B * HID;           // 2 buffers
  int*   flags = (int*)(denb + 2 * B);

  keys_kernel<<<dim3(1024), dim3(256), 0, stream>>>(enc, Wk, keys);
  main_kernel<<<dim3(G), dim3(BS), 0, stream>>>(
      x, enc, Wq, v, Wih, Whh, bih, bhh, Wfc, bfc,
      keys, hbuf, cbuf, qbuf, ctxb, denb, flags, (float*)d_out);
}